// Round 16
// baseline (2027.878 us; speedup 1.0000x reference)
//
#include <hip/hip_runtime.h>

typedef __bf16 bf16x8 __attribute__((ext_vector_type(8)));
typedef float f32x4 __attribute__((ext_vector_type(4)));
typedef unsigned short u16;
typedef unsigned int u32;

#define T_ 64
#define B_ 1024
#define H_ 1024
#define G4_ 4096
#define HB_ (B_ * H_)
#define NBLK_ 512
#define PARTSZ_ (B_ * 2 * 64)

__device__ inline u16 f2bf(float f) {
  u32 u = __float_as_uint(f);
  u32 r = (u + 0x7fffu + ((u >> 16) & 1u)) >> 16;  // RNE
  return (u16)r;
}

__device__ inline uint2 cvt4(float4 v) {
  uint2 r;
  r.x = (u32)f2bf(v.x) | ((u32)f2bf(v.y) << 16);
  r.y = (u32)f2bf(v.z) | ((u32)f2bf(v.w) << 16);
  return r;
}

__device__ __forceinline__ void gload16(const void* g, void* l) {
  __builtin_amdgcn_global_load_lds(
      (const __attribute__((address_space(1))) unsigned int*)g,
      (__attribute__((address_space(3))) unsigned int*)l, 16, 0, 0);
}

// write-through 2B store: data lands at the coherence point (L3), never dirty in L2.
__device__ __forceinline__ void store_wt16(u16* p, u16 v) {
  asm volatile("global_store_short %0, %1, off sc0 sc1" :: "v"(p), "v"((u32)v) : "memory");
}

__device__ inline float fsig(float x) { return 1.f / (1.f + __expf(-x)); }
__device__ inline float ftanh(float x) {
  float e = __expf(2.f * x);
  return 1.f - 2.f / (e + 1.f);
}

// ---------- prep: WihP/WhhP gate-interleaved-row bf16 [4096][1024], bcP permuted bias,
// h0slot=bf16(h0), flags[64][512]=0.  Permutation: n' = (j>>4)*64 + gate*16 + (j&15)
__global__ void prep_kernel(const float* __restrict__ W_ih, const float* __restrict__ W_hh,
                            const float* __restrict__ b_ih, const float* __restrict__ b_hh,
                            const float* __restrict__ h0,
                            u16* __restrict__ WihP, u16* __restrict__ WhhP,
                            float* __restrict__ bcP, u16* __restrict__ h0slot,
                            u32* __restrict__ flags) {
  int bid = blockIdx.x, tid = threadIdx.x;
  if (bid < 4096) {
    int np = bid;
    int gate = (np >> 4) & 3;
    int j = ((np >> 6) << 4) | (np & 15);
    size_t srow = (size_t)(gate * 1024 + j) * 1024;
    int base = tid << 2;
    *(uint2*)(WihP + (size_t)np * 1024 + base) = cvt4(*(const float4*)(W_ih + srow + base));
    *(uint2*)(WhhP + (size_t)np * 1024 + base) = cvt4(*(const float4*)(W_hh + srow + base));
  } else if (bid < 5120) {
    int i = ((bid - 4096) * 256 + tid) << 2;
    *(uint2*)(h0slot + i) = cvt4(*(const float4*)(h0 + i));
  } else if (bid == 5120) {
#pragma unroll
    for (int q = 0; q < 16; ++q) {
      int np = q * 256 + tid;
      int gate = (np >> 4) & 3;
      int j = ((np >> 6) << 4) | (np & 15);
      int srcn = gate * 1024 + j;
      bcP[np] = b_ih[srcn] + b_hh[srcn];
    }
  } else {
    int idx = ((bid - 5121) * 256 + tid) << 2;  // 32 blocks x 1024 u32 = 32768
    *(uint4*)(flags + idx) = uint4{0u, 0u, 0u, 0u};
  }
}

// ---------- gather ALL 64 steps: XEall[t][b][:] = bf16(emb[x[b,t]])
__global__ void gather_kernel(const int* __restrict__ x, const float* __restrict__ emb,
                              u16* __restrict__ XEall) {
  int b = blockIdx.x, tc = blockIdx.y;
  int row = x[b * T_ + tc];
  int e = threadIdx.x << 2;
  float4 v = *(const float4*)(emb + (size_t)row * H_ + e);
  *(uint2*)(XEall + ((size_t)tc * B_ + b) * H_ + e) = cvt4(v);
}

// xproj phase, run in rec's wait bubble: this block's own 128x64 GX tile for step
// (XEt) -> LDS gx buffer at gxOff. Wave-private output (wave qm writes rows qm*16..,
// and only that wave reads them next step). Reuses A/B staging dbufs + vmcnt(3).
#define XPROJ_PHASE(XEt, gxOff) do {                                          \
    _Pragma("unroll")                                                         \
    for (int s = 0; s < 2; ++s) gload16((XEt) + offA[s], smem + betaS[s]);    \
    gload16(WihP + offB, smem + 32768 + betaB);                               \
    f32x4 acc2[4] = {};                                                       \
    _Pragma("unroll")                                                         \
    for (int kt = 0; kt < 16; ++kt) {                                         \
      const int cur = kt & 1;                                                 \
      const int abase = cur * 16384;                                          \
      const int bbase = 32768 + cur * 8192;                                   \
      if (kt < 15) {                                                          \
        const int nab = (cur ^ 1) * 16384;                                    \
        const int nbb = 32768 + (cur ^ 1) * 8192;                             \
        const int kadv = (kt + 1) * 64;                                       \
        _Pragma("unroll")                                                     \
        for (int s = 0; s < 2; ++s)                                           \
          gload16((XEt) + offA[s] + kadv, smem + nab + betaS[s]);             \
        gload16(WihP + offB + kadv, smem + nbb + betaB);                      \
        asm volatile("s_waitcnt vmcnt(3)" ::: "memory");                      \
      } else {                                                                \
        asm volatile("s_waitcnt vmcnt(0)" ::: "memory");                      \
      }                                                                       \
      __builtin_amdgcn_s_barrier();                                           \
      __builtin_amdgcn_sched_barrier(0);                                      \
      _Pragma("unroll")                                                       \
      for (int kk = 0; kk < 2; ++kk) {                                        \
        const int colb = kk * 64 + ksel;                                      \
        bf16x8 af, bfr[4];                                                    \
        {                                                                     \
          int row = qm * 16 + rsel;                                           \
          af = *(const bf16x8*)(smem + abase + row * 128 + (colb ^ ((row & 7) << 4))); \
        }                                                                     \
        _Pragma("unroll")                                                     \
        for (int ni = 0; ni < 4; ++ni) {                                      \
          int row = ni * 16 + rsel;                                           \
          bfr[ni] = *(const bf16x8*)(smem + bbase + row * 128 + (colb ^ ((row & 7) << 4))); \
        }                                                                     \
        _Pragma("unroll")                                                     \
        for (int ni = 0; ni < 4; ++ni)                                        \
          acc2[ni] = __builtin_amdgcn_mfma_f32_16x16x32_bf16(af, bfr[ni], acc2[ni], 0, 0, 0); \
      }                                                                       \
      __builtin_amdgcn_s_barrier();                                           \
      __builtin_amdgcn_sched_barrier(0);                                      \
    }                                                                         \
    _Pragma("unroll")                                                         \
    for (int ni = 0; ni < 4; ++ni) {                                          \
      _Pragma("unroll")                                                       \
      for (int r2 = 0; r2 < 4; ++r2) {                                        \
        int grow = qm * 16 + rbase + r2;                                      \
        int col = ni * 16 + cbase;                                            \
        *(u16*)(smem + (gxOff) + ((grow << 7) | ((col << 1) ^ ((grow & 7) << 4)))) = \
            f2bf(acc2[ni][r2] + bc4[ni]);                                     \
      }                                                                       \
    }                                                                         \
  } while (0)

// ---------- persistent recurrent kernel: all 64 steps, NO fences, xproj FUSED.
// Per step: rec K-loop (gates += h @ Whh^T) -> cell (gx from LDS, c in regs, h WT
// stores) -> flag -> head partials -> XPROJ_PHASE computes next step's GX tile into
// the LDS gx dbuf, filling the producer-wait bubble. GX never touches HBM.
__global__ void __launch_bounds__(512, 4) rec_kernel(
    const u16* __restrict__ h0slot, u16* __restrict__ hring,
    const u16* __restrict__ WhhP, const u16* __restrict__ WihP,
    const u16* __restrict__ XEall, const float* __restrict__ c0,
    const float* __restrict__ bcP, float* __restrict__ partAll,
    const float* __restrict__ Wout, u32* __restrict__ flags) {
  __shared__ char smem[81920];  // A dbuf 2x16K | B dbuf 2x8K @32768 | gx dbuf 2x16K @49152
  const int tid = threadIdx.x;
  const int lane = tid & 63;
  const int qm = tid >> 6;  // wave = m-slice [0,8), 16 rows each
  const int hbid = blockIdx.x;
  const int L = (hbid & 7) * 64 + (hbid >> 3);  // XCD swizzle: W n-slice per XCD
  const int bx = L >> 3;   // [0,64): n-tile
  const int by = L & 7;    // [0,8): m-tile
  const int n0 = bx * 64;
  const int m0 = by * 128;

  int offA[2], betaS[2];
  int offB, betaB;
#pragma unroll
  for (int s = 0; s < 2; ++s) {
    int beta = (s * 512 + tid) * 16;             // 0..16K
    int row = beta >> 7;
    int colu = (beta & 127) ^ ((row & 7) << 4);
    offA[s] = (m0 + row) * 1024 + (colu >> 1);   // [1024][1024] bf16 (h slabs AND XE slabs)
    betaS[s] = beta;
  }
  {
    int beta = tid * 16;                         // 0..8K
    int row = beta >> 7;
    int colu = (beta & 127) ^ ((row & 7) << 4);
    offB = (n0 + row) * 1024 + (colu >> 1);      // [4096][1024] bf16 (WhhP AND WihP)
    betaB = beta;
  }

  const int rsel = lane & 15;
  const int ksel = (lane >> 4) << 4;
  const int rbase = (lane >> 4) << 2;
  const int cbase = lane & 15;
  const int j = bx * 16 + cbase;
  const float w0 = Wout[j], w1 = Wout[1024 + j];
  float bc4[4];
#pragma unroll
  for (int ni = 0; ni < 4; ++ni) bc4[ni] = bcP[n0 + ni * 16 + cbase];

  // cell state lives in registers for the whole sequence (4 rows per thread)
  float creg[4];
#pragma unroll
  for (int r = 0; r < 4; ++r)
    creg[r] = c0[(size_t)(m0 + qm * 16 + rbase + r) * H_ + j];

  // prologue: GX(0) tile -> gx buffer 0 (fills while other blocks still launching)
  XPROJ_PHASE(XEall, 49152);

#pragma unroll 1
  for (int t = 0; t < T_; ++t) {
    // B(Whh) tile 0 -> buffer 0: barrier-independent, issue before the poll.
    gload16(WhhP + offB, smem + 32768 + betaB);

    if (t) {
      // group barrier: wait for the 64 same-by blocks (they wrote our h rows, step t-1)
      if (tid < 64) {
        const u32* fg = flags + (size_t)(t - 1) * NBLK_ + by * 64;
        int guard = 0;
        while (true) {
          u32 v = __hip_atomic_load(fg + tid, __ATOMIC_RELAXED, __HIP_MEMORY_SCOPE_AGENT);
          if (__all(v != 0)) break;
          __builtin_amdgcn_s_sleep(4);
          if (++guard > (1 << 18)) break;  // bounded: fail loud, never hang
        }
      }
    }
    __syncthreads();  // no acquire fence needed (h buffer fresh); also fences gx/XPROJ LDS reuse

    // h ring: step t reads hring[t-1] (t=0 -> h0slot), writes hring[t]
    const u16* hbR = t ? (hring + (size_t)(t - 1) * HB_) : h0slot;
    u16* hbW = hring + (size_t)t * HB_;

    // A(h) tile 0 (needs the barrier)
#pragma unroll
    for (int s = 0; s < 2; ++s) gload16(hbR + offA[s], smem + betaS[s]);

    f32x4 acc[4] = {};
#pragma unroll
    for (int kt = 0; kt < 16; ++kt) {
      const int cur = kt & 1;
      const int abase = cur * 16384;
      const int bbase = 32768 + cur * 8192;
      if (kt < 15) {
        const int nab = (cur ^ 1) * 16384;
        const int nbb = 32768 + (cur ^ 1) * 8192;
        const int kadv = (kt + 1) * 64;
#pragma unroll
        for (int s = 0; s < 2; ++s) gload16(hbR + offA[s] + kadv, smem + nab + betaS[s]);
        gload16(WhhP + offB + kadv, smem + nbb + betaB);
        // steady: queue = [3 tile_kt, 3 tile_kt+1] -> vmcnt(3) drains tile kt.
        // kt0: queue = [2 A0, 3 tile1] (B0 drained by syncthreads) -> vmcnt(3) drains A0.
        asm volatile("s_waitcnt vmcnt(3)" ::: "memory");
      } else {
        asm volatile("s_waitcnt vmcnt(0)" ::: "memory");
      }
      __builtin_amdgcn_s_barrier();
      __builtin_amdgcn_sched_barrier(0);
#pragma unroll
      for (int kk = 0; kk < 2; ++kk) {
        const int colb = kk * 64 + ksel;
        bf16x8 af, bfr[4];
        {
          int row = qm * 16 + rsel;
          af = *(const bf16x8*)(smem + abase + row * 128 + (colb ^ ((row & 7) << 4)));
        }
#pragma unroll
        for (int ni = 0; ni < 4; ++ni) {
          int row = ni * 16 + rsel;
          bfr[ni] = *(const bf16x8*)(smem + bbase + row * 128 + (colb ^ ((row & 7) << 4)));
        }
#pragma unroll
        for (int ni = 0; ni < 4; ++ni)
          acc[ni] = __builtin_amdgcn_mfma_f32_16x16x32_bf16(af, bfr[ni], acc[ni], 0, 0, 0);
      }
      __builtin_amdgcn_s_barrier();
      __builtin_amdgcn_sched_barrier(0);
    }

    // epilogue pass 1: gates = acc + gx(LDS, written by THIS wave last step);
    // cell on register c; write-through h stores.
    const char* lsGX = smem + 49152 + (t & 1) * 16384;
#pragma unroll
    for (int r = 0; r < 4; ++r) {
      int grow = qm * 16 + rbase + r;  // row within 128-tile
      int b = m0 + grow;
      int gxswz = (grow & 7) << 4;
      float gx0 = __uint_as_float(
          (u32)*(const u16*)(lsGX + ((grow << 7) | ((cbase << 1) ^ gxswz))) << 16);
      float gx1 = __uint_as_float(
          (u32)*(const u16*)(lsGX + ((grow << 7) | ((((16 + cbase) << 1)) ^ gxswz))) << 16);
      float gx2 = __uint_as_float(
          (u32)*(const u16*)(lsGX + ((grow << 7) | ((((32 + cbase) << 1)) ^ gxswz))) << 16);
      float gx3 = __uint_as_float(
          (u32)*(const u16*)(lsGX + ((grow << 7) | ((((48 + cbase) << 1)) ^ gxswz))) << 16);
      float gi = acc[0][r] + gx0;
      float gf = acc[1][r] + gx1;
      float gg = acc[2][r] + gx2;
      float go = acc[3][r] + gx3;
      float c2 = fsig(gf) * creg[r] + fsig(gi) * ftanh(gg);
      float h2 = fsig(go) * ftanh(c2);
      creg[r] = c2;
      store_wt16(hbW + (size_t)b * H_ + j, f2bf(h2));
    }

    // signal ASAP: h stores at coherence point once vmcnt drains
    asm volatile("s_waitcnt vmcnt(0)" ::: "memory");
    __syncthreads();
    if (tid == 0)
      __hip_atomic_store(flags + (size_t)t * NBLK_ + by * 64 + bx, 1u,
                         __ATOMIC_RELAXED, __HIP_MEMORY_SCOPE_AGENT);

    // head partials (off critical path)
    float* partW = partAll + (size_t)t * PARTSZ_;
#pragma unroll
    for (int r = 0; r < 4; ++r) {
      int b = m0 + qm * 16 + rbase + r;
      float p0 = creg[r] * w0, p1 = creg[r] * w1;
#pragma unroll
      for (int off = 1; off < 16; off <<= 1) {
        p0 += __shfl_xor(p0, off);
        p1 += __shfl_xor(p1, off);
      }
      if (cbase == 0) {
        partW[(b << 7) + bx] = p0;
        partW[(b << 7) + 64 + bx] = p1;
      }
    }

    // xproj for step t+1 into gx[(t+1)&1] — fills the producer-wait bubble.
    if (t + 1 < T_) {
      const u16* XEn = XEall + (size_t)(t + 1) * HB_;
      const int gxOff = 49152 + ((t + 1) & 1) * 16384;
      XPROJ_PHASE(XEn, gxOff);
    }
  }
}

// ---------- final: reduce ALL steps' partials -> out[t] log-softmax; t=63 also raw out_final
__global__ void final_kernel(const float* __restrict__ partAll, const float* __restrict__ bout,
                             float* __restrict__ out) {
  int gid = blockIdx.x * 256 + threadIdx.x;  // 131072 = 64 t x 1024 b x 2 cls
  int t = gid >> 11;
  int r = gid & 2047;
  int b = r >> 1, cls = r & 1;
  const float4* pp = (const float4*)(partAll + (size_t)t * PARTSZ_ + (b << 7) + cls * 64);
  float4 sv = {0.f, 0.f, 0.f, 0.f};
#pragma unroll
  for (int q = 0; q < 16; ++q) {
    float4 v = pp[q];
    sv.x += v.x; sv.y += v.y; sv.z += v.z; sv.w += v.w;
  }
  float l = sv.x + sv.y + sv.z + sv.w + bout[cls];
  float other = __shfl_xor(l, 1);
  float m = fmaxf(l, other);
  float ls = m + __logf(__expf(l - m) + __expf(other - m));
  out[(size_t)t * (B_ * 2) + b * 2 + cls] = l - ls;
  if (t == 63) out[(size_t)T_ * (B_ * 2) + b * 2 + cls] = l;  // out_final raw
}

extern "C" void kernel_launch(void* const* d_in, const int* in_sizes, int n_in,
                              void* d_out, int out_size, void* d_ws, size_t ws_size,
                              hipStream_t stream) {
  const int* x      = (const int*)d_in[0];
  const float* emb  = (const float*)d_in[1];
  const float* W_ih = (const float*)d_in[2];
  const float* W_hh = (const float*)d_in[3];
  const float* b_ih = (const float*)d_in[4];
  const float* b_hh = (const float*)d_in[5];
  const float* W_out = (const float*)d_in[6];
  const float* b_out = (const float*)d_in[7];
  const float* h0   = (const float*)d_in[8];
  const float* c0   = (const float*)d_in[9];
  float* out = (float*)d_out;

  // workspace (~306 MB): GXall eliminated (GX lives only in LDS now).
  char* w = (char*)d_ws;
  u16* WihP = (u16*)w;   w += (size_t)G4_ * H_ * 2;             // 8 MB
  u16* WhhP = (u16*)w;   w += (size_t)G4_ * H_ * 2;             // 8 MB
  u16* XEall = (u16*)w;  w += (size_t)T_ * HB_ * 2;             // 128 MB (live all of rec)
  u16* hring = (u16*)w;  w += (size_t)T_ * HB_ * 2;             // 128 MB (fresh slab/step)
  u16* h0slot = (u16*)w; w += (size_t)HB_ * 2;                  // 2 MB
  float* bcP = (float*)w;     w += (size_t)G4_ * 4;
  float* partAll = (float*)w; w += (size_t)T_ * PARTSZ_ * 4;    // 32 MB
  u32* flags = (u32*)w;       w += (size_t)T_ * NBLK_ * 4;      // 128 KB

  prep_kernel<<<5153, 256, 0, stream>>>(W_ih, W_hh, b_ih, b_hh, h0,
                                        WihP, WhhP, bcP, h0slot, flags);
  gather_kernel<<<dim3(B_, T_), 256, 0, stream>>>(x, emb, XEall);
  rec_kernel<<<NBLK_, 512, 0, stream>>>(h0slot, hring, WhhP, WihP, XEall, c0, bcP,
                                        partAll, W_out, flags);
  final_kernel<<<512, 256, 0, stream>>>(partAll, b_out, out);
}

// Round 17
// 1721.219 us; speedup vs baseline: 1.1782x; 1.1782x over previous
//
#include <hip/hip_runtime.h>

typedef __bf16 bf16x8 __attribute__((ext_vector_type(8)));
typedef float f32x4 __attribute__((ext_vector_type(4)));
typedef unsigned short u16;
typedef unsigned int u32;

#define T_ 64
#define B_ 1024
#define H_ 1024
#define G4_ 4096
#define HB_ (B_ * H_)
#define NBLK_ 256
#define PARTSZ_ (B_ * 2 * 64)

__device__ inline u16 f2bf(float f) {
  u32 u = __float_as_uint(f);
  u32 r = (u + 0x7fffu + ((u >> 16) & 1u)) >> 16;  // RNE
  return (u16)r;
}

__device__ inline uint2 cvt4(float4 v) {
  uint2 r;
  r.x = (u32)f2bf(v.x) | ((u32)f2bf(v.y) << 16);
  r.y = (u32)f2bf(v.z) | ((u32)f2bf(v.w) << 16);
  return r;
}

__device__ __forceinline__ void gload16(const void* g, void* l) {
  __builtin_amdgcn_global_load_lds(
      (const __attribute__((address_space(1))) unsigned int*)g,
      (__attribute__((address_space(3))) unsigned int*)l, 16, 0, 0);
}

// non-temporal variant (CPol NT): stream, don't allocate in L2/L3.
__device__ __forceinline__ void gload16_nt(const void* g, void* l) {
  __builtin_amdgcn_global_load_lds(
      (const __attribute__((address_space(1))) unsigned int*)g,
      (__attribute__((address_space(3))) unsigned int*)l, 16, 0, 2);
}

// write-through 2B store: data lands at the coherence point (L3), never dirty in L2.
__device__ __forceinline__ void store_wt16(u16* p, u16 v) {
  asm volatile("global_store_short %0, %1, off sc0 sc1" :: "v"(p), "v"((u32)v) : "memory");
}

__device__ inline float fsig(float x) { return 1.f / (1.f + __expf(-x)); }
__device__ inline float ftanh(float x) {
  float e = __expf(2.f * x);
  return 1.f - 2.f / (e + 1.f);
}

// ---------- prep: WihP/WhhP gate-interleaved-row bf16 [4096][1024], bcP permuted bias,
// h0slot=bf16(h0), flags[64][256]=0.  Permutation: n' = (j>>4)*64 + gate*16 + (j&15)
__global__ void prep_kernel(const float* __restrict__ W_ih, const float* __restrict__ W_hh,
                            const float* __restrict__ b_ih, const float* __restrict__ b_hh,
                            const float* __restrict__ h0,
                            u16* __restrict__ WihP, u16* __restrict__ WhhP,
                            float* __restrict__ bcP, u16* __restrict__ h0slot,
                            u32* __restrict__ flags) {
  int bid = blockIdx.x, tid = threadIdx.x;
  if (bid < 4096) {
    int np = bid;
    int gate = (np >> 4) & 3;
    int j = ((np >> 6) << 4) | (np & 15);
    size_t srow = (size_t)(gate * 1024 + j) * 1024;
    int base = tid << 2;
    *(uint2*)(WihP + (size_t)np * 1024 + base) = cvt4(*(const float4*)(W_ih + srow + base));
    *(uint2*)(WhhP + (size_t)np * 1024 + base) = cvt4(*(const float4*)(W_hh + srow + base));
  } else if (bid < 5120) {
    int i = ((bid - 4096) * 256 + tid) << 2;
    *(uint2*)(h0slot + i) = cvt4(*(const float4*)(h0 + i));
  } else if (bid == 5120) {
#pragma unroll
    for (int q = 0; q < 16; ++q) {
      int np = q * 256 + tid;
      int gate = (np >> 4) & 3;
      int j = ((np >> 6) << 4) | (np & 15);
      int srcn = gate * 1024 + j;
      bcP[np] = b_ih[srcn] + b_hh[srcn];
    }
  } else {
    int idx = ((bid - 5121) * 256 + tid) << 2;  // 16 blocks x 1024 u32 = 16384
    *(uint4*)(flags + idx) = uint4{0u, 0u, 0u, 0u};
  }
}

// ---------- gather ALL 64 steps: XEall[t][b][:] = bf16(emb[x[b,t]])
__global__ void gather_kernel(const int* __restrict__ x, const float* __restrict__ emb,
                              u16* __restrict__ XEall) {
  int b = blockIdx.x, tc = blockIdx.y;
  int row = x[b * T_ + tc];
  int e = threadIdx.x << 2;
  float4 v = *(const float4*)(emb + (size_t)row * H_ + e);
  *(uint2*)(XEall + ((size_t)tc * B_ + b) * H_ + e) = cvt4(v);
}

// ---------- x-projection big GEMM, ONE dispatch (r15-proven): M = 65536, N = 4096, K = 1024.
// 256x128 tile, 512 threads = 8 waves (4m x 2n of 64x64), BK=64, single LDS buffer.
__global__ void __launch_bounds__(512, 4) xproj_kernel(
    const u16* __restrict__ XEc, const u16* __restrict__ WihP,
    const float* __restrict__ bcP, u16* __restrict__ GXc) {
  __shared__ char smem[49152];  // lsA [256][128B] (32K) + lsB [128][128B] (16K)
  const int tid = threadIdx.x;
  const int lane = tid & 63;
  const int wave = tid >> 6;
  const int wm = wave >> 1;  // [0,4)
  const int wn = wave & 1;   // [0,2)
  const int hbid = blockIdx.x;        // 8192 = 8 XCD x 1024
  const int xcd = hbid & 7;
  const int s10 = hbid >> 3;          // [0,1024)
  const int mg = s10 >> 6;            // [0,16) groups of 2 m-tiles
  const int rem = s10 & 63;
  const int n0 = (rem >> 1) * 128;    // 32 n-tiles, inner sweep
  const int m0 = (xcd * 32 + mg * 2 + (rem & 1)) * 256;  // 256 m-tiles, XCD-private

  const u16* srcA[4];
  const u16* srcB[2];
  int betaA[4], betaB[2];
#pragma unroll
  for (int s = 0; s < 4; ++s) {
    int beta = (s * 512 + tid) * 16;             // 0..32K
    int row = beta >> 7;                         // [0,256)
    int colu = (beta & 127) ^ ((row & 7) << 4);  // pre-swizzled source col
    srcA[s] = XEc + (size_t)(m0 + row) * 1024 + (colu >> 1);
    betaA[s] = beta;
  }
#pragma unroll
  for (int s = 0; s < 2; ++s) {
    int beta = (s * 512 + tid) * 16;             // 0..16K
    int row = beta >> 7;                         // [0,128)
    int colu = (beta & 127) ^ ((row & 7) << 4);
    srcB[s] = WihP + (size_t)(n0 + row) * 1024 + (colu >> 1);
    betaB[s] = 32768 + beta;
  }

  f32x4 acc[4][4] = {};
  const int rsel = lane & 15;
  const int ksel = (lane >> 4) << 4;

  for (int kt = 0; kt < 16; ++kt) {
#pragma unroll
    for (int s = 0; s < 4; ++s) gload16(srcA[s], smem + betaA[s]);
#pragma unroll
    for (int s = 0; s < 2; ++s) gload16(srcB[s], smem + betaB[s]);
#pragma unroll
    for (int s = 0; s < 4; ++s) srcA[s] += 64;
#pragma unroll
    for (int s = 0; s < 2; ++s) srcB[s] += 64;
    __syncthreads();
#pragma unroll
    for (int kk = 0; kk < 2; ++kk) {
      const int colb = kk * 64 + ksel;
      bf16x8 af[4], bfr[4];
#pragma unroll
      for (int mi = 0; mi < 4; ++mi) {
        int row = wm * 64 + mi * 16 + rsel;
        af[mi] = *(const bf16x8*)(smem + row * 128 + (colb ^ ((row & 7) << 4)));
      }
#pragma unroll
      for (int ni = 0; ni < 4; ++ni) {
        int row = wn * 64 + ni * 16 + rsel;
        bfr[ni] = *(const bf16x8*)(smem + 32768 + row * 128 + (colb ^ ((row & 7) << 4)));
      }
#pragma unroll
      for (int mi = 0; mi < 4; ++mi)
#pragma unroll
        for (int ni = 0; ni < 4; ++ni)
          acc[mi][ni] = __builtin_amdgcn_mfma_f32_16x16x32_bf16(af[mi], bfr[ni], acc[mi][ni], 0, 0, 0);
    }
    __syncthreads();
  }

  const int rbase = (lane >> 4) << 2;
  const int cbase = lane & 15;
  float bc[4];
#pragma unroll
  for (int ni = 0; ni < 4; ++ni) bc[ni] = bcP[n0 + wn * 64 + ni * 16 + cbase];
#pragma unroll
  for (int mi = 0; mi < 4; ++mi) {
#pragma unroll
    for (int ni = 0; ni < 4; ++ni) {
      int gc = n0 + wn * 64 + ni * 16 + cbase;
#pragma unroll
      for (int r = 0; r < 4; ++r) {
        int gm = m0 + wm * 64 + mi * 16 + rbase + r;
        GXc[(size_t)gm * G4_ + gc] = f2bf(acc[mi][ni][r] + bc[ni]);
      }
    }
  }
}

// ---------- persistent recurrent kernel: 256 blocks, 4 waves of 64x64 tiles (acc[4][4]).
// FLOP per LDS byte doubled vs r13 (32 vs 16) -> attacks the measured LDS-BW bound.
// Block tile 128 rows x 128 n'-cols (bx<32, by<8). Wave (qm,qn): rows qm*64, cols qn*64
// = j-group qn (all 4 gates wave-local). h via WT stores + fresh ring; per-group flags
// (32 producers); GX dbuf in LDS (32KB tiles), GX(t+1) issued at kt15 (vmcnt(8) keeps
// it in flight); c in registers (creg[4][4]).
__global__ void __launch_bounds__(256, 1) rec_kernel(
    const u16* __restrict__ h0slot, u16* __restrict__ hring,
    const u16* __restrict__ WhhP, const u16* __restrict__ GXall,
    const float* __restrict__ c0, float* __restrict__ partAll,
    const float* __restrict__ Wout, u32* __restrict__ flags) {
  __shared__ char smem[131072];  // A dbuf 2x16K | B dbuf 2x16K @32768 | GX dbuf 2x32K @65536
  const int tid = threadIdx.x;
  const int lane = tid & 63;
  const int wave = tid >> 6;
  const int qm = wave >> 1;  // row-half
  const int qn = wave & 1;   // col-half = j-group
  const int hbid = blockIdx.x;
  const int L = (hbid & 7) * 32 + (hbid >> 3);  // XCD swizzle
  const int bx = L >> 3;   // [0,32): n-tile (128 n' cols)
  const int by = L & 7;    // [0,8): m-tile (128 rows)
  const int n0 = bx * 128;
  const int m0 = by * 128;

  int offA[4], offB[4], betaS[4];
  int offGX[8], betaG[8];
#pragma unroll
  for (int s = 0; s < 4; ++s) {
    int beta = (s * 256 + tid) * 16;             // 0..16K
    int row = beta >> 7;                         // 128B rows (BK=64)
    int colu = (beta & 127) ^ ((row & 7) << 4);
    offA[s] = (m0 + row) * 1024 + (colu >> 1);
    offB[s] = (n0 + row) * 1024 + (colu >> 1);
    betaS[s] = beta;
  }
#pragma unroll
  for (int s = 0; s < 8; ++s) {
    int beta = (s * 256 + tid) * 16;             // 0..32K
    int row = beta >> 8;                         // 256B rows (128 cols bf16)
    int colu = (beta & 255) ^ ((row & 7) << 4);
    offGX[s] = (m0 + row) * G4_ + n0 + (colu >> 1);
    betaG[s] = beta;
  }

  const int rsel = lane & 15;
  const int ksel = (lane >> 4) << 4;
  const int rbase = (lane >> 4) << 2;
  const int cbase = lane & 15;
  const int j = bx * 32 + qn * 16 + cbase;
  const float w0 = Wout[j], w1 = Wout[1024 + j];

  // cell state in registers: 16 rows per thread (mi 0..3 x r 0..3) at column j
  float creg[4][4];
#pragma unroll
  for (int mi = 0; mi < 4; ++mi)
#pragma unroll
    for (int r = 0; r < 4; ++r)
      creg[mi][r] = c0[(size_t)(m0 + qm * 64 + mi * 16 + rbase + r) * H_ + j];

  // GX(0) -> gx buffer 0 (NT; drained by kt0's vmcnt(8) of step 0)
#pragma unroll
  for (int s = 0; s < 8; ++s) gload16_nt(GXall + offGX[s], smem + 65536 + betaG[s]);

#pragma unroll 1
  for (int t = 0; t < T_; ++t) {
    // B(Whh) tile 0 -> buffer 0: barrier-independent, issue before the poll.
#pragma unroll
    for (int s = 0; s < 4; ++s) gload16(WhhP + offB[s], smem + 32768 + betaS[s]);

    if (t) {
      // group barrier: wait for the 32 same-by blocks (they wrote our h rows, step t-1)
      if (tid < 32) {
        const u32* fg = flags + (size_t)(t - 1) * NBLK_ + by * 32;
        int guard = 0;
        while (true) {
          u32 v = __hip_atomic_load(fg + tid, __ATOMIC_RELAXED, __HIP_MEMORY_SCOPE_AGENT);
          if (__all(tid >= 32 || v != 0)) break;
          __builtin_amdgcn_s_sleep(4);
          if (++guard > (1 << 18)) break;  // bounded: fail loud, never hang
        }
      } else {
        // non-polling lanes still participate in wave-level __all via their own wave
      }
      __syncthreads();  // no acquire fence: h buffer fresh, L2 never cached it
    }

    // h ring: step t reads hring[t-1] (t=0 -> h0slot), writes hring[t]
    const u16* hbR = t ? (hring + (size_t)(t - 1) * HB_) : h0slot;
    u16* hbW = hring + (size_t)t * HB_;

    // A(h) tile 0 (needs the barrier)
#pragma unroll
    for (int s = 0; s < 4; ++s) gload16(hbR + offA[s], smem + betaS[s]);

    f32x4 acc[4][4] = {};
#pragma unroll
    for (int kt = 0; kt < 16; ++kt) {
      const int cur = kt & 1;
      const int abase = cur * 16384;
      const int bbase = 32768 + cur * 16384;
      if (kt < 15) {
        const int nab = (cur ^ 1) * 16384;
        const int nbb = 32768 + (cur ^ 1) * 16384;
        const int kadv = (kt + 1) * 64;
#pragma unroll
        for (int s = 0; s < 4; ++s) gload16(hbR + offA[s] + kadv, smem + nab + betaS[s]);
#pragma unroll
        for (int s = 0; s < 4; ++s) gload16(WhhP + offB[s] + kadv, smem + nbb + betaS[s]);
        // steady: queue = [8 tile_kt, 8 tile_kt+1] -> vmcnt(8) drains tile kt.
        // kt0: queue = [8 GX, 4 B0, 4 A0, 8 tile1] -> vmcnt(8) drains GX+tile0.
        asm volatile("s_waitcnt vmcnt(8)" ::: "memory");
      } else {
        if (t + 1 < T_) {
          // GX(t+1) NT prefetch: newest 8 in queue; vmcnt(8) drains tile kt15.
          const u16* GXn = GXall + (size_t)(t + 1) * B_ * G4_;
          const int gxb = 65536 + ((t + 1) & 1) * 32768;
#pragma unroll
          for (int s = 0; s < 8; ++s) gload16_nt(GXn + offGX[s], smem + gxb + betaG[s]);
          asm volatile("s_waitcnt vmcnt(8)" ::: "memory");
        } else {
          asm volatile("s_waitcnt vmcnt(0)" ::: "memory");
        }
      }
      __builtin_amdgcn_s_barrier();
      __builtin_amdgcn_sched_barrier(0);
#pragma unroll
      for (int kk = 0; kk < 2; ++kk) {
        const int colb = kk * 64 + ksel;
        bf16x8 af[4], bfr[4];
#pragma unroll
        for (int mi = 0; mi < 4; ++mi) {
          int row = qm * 64 + mi * 16 + rsel;
          af[mi] = *(const bf16x8*)(smem + abase + row * 128 + (colb ^ ((row & 7) << 4)));
        }
#pragma unroll
        for (int ni = 0; ni < 4; ++ni) {
          int row = qn * 64 + ni * 16 + rsel;
          bfr[ni] = *(const bf16x8*)(smem + bbase + row * 128 + (colb ^ ((row & 7) << 4)));
        }
#pragma unroll
        for (int mi = 0; mi < 4; ++mi)
#pragma unroll
          for (int ni = 0; ni < 4; ++ni)
            acc[mi][ni] = __builtin_amdgcn_mfma_f32_16x16x32_bf16(af[mi], bfr[ni], acc[mi][ni], 0, 0, 0);
      }
      __builtin_amdgcn_s_barrier();
      __builtin_amdgcn_sched_barrier(0);
    }

    // epilogue pass 1: gates = acc + gx(LDS); cell on register c; write-through h.
    // gx col for gate g: n'-local = qn*64 + g*16 + cbase (j-group qn, 256B rows).
    const char* lsGX = smem + 65536 + (t & 1) * 32768;
#pragma unroll
    for (int mi = 0; mi < 4; ++mi) {
#pragma unroll
      for (int r = 0; r < 4; ++r) {
        int grow = qm * 64 + mi * 16 + rbase + r;  // row within 128-tile
        int b = m0 + grow;
        int gxswz = (grow & 7) << 4;
        const char* gxrow = lsGX + (grow << 8);
        float gx0 = __uint_as_float(
            (u32)*(const u16*)(gxrow + ((((qn * 64 + cbase) << 1)) ^ gxswz)) << 16);
        float gx1 = __uint_as_float(
            (u32)*(const u16*)(gxrow + ((((qn * 64 + 16 + cbase) << 1)) ^ gxswz)) << 16);
        float gx2 = __uint_as_float(
            (u32)*(const u16*)(gxrow + ((((qn * 64 + 32 + cbase) << 1)) ^ gxswz)) << 16);
        float gx3 = __uint_as_float(
            (u32)*(const u16*)(gxrow + ((((qn * 64 + 48 + cbase) << 1)) ^ gxswz)) << 16);
        float gi = acc[mi][0][r] + gx0;
        float gf = acc[mi][1][r] + gx1;
        float gg = acc[mi][2][r] + gx2;
        float go = acc[mi][3][r] + gx3;
        float c2 = fsig(gf) * creg[mi][r] + fsig(gi) * ftanh(gg);
        float h2 = fsig(go) * ftanh(c2);
        creg[mi][r] = c2;
        store_wt16(hbW + (size_t)b * H_ + j, f2bf(h2));
      }
    }

    // drain the 16 h stores (GX(t+1)'s 8 loads are newest -> stay in flight)
    if (t + 1 < T_) {
      asm volatile("s_waitcnt vmcnt(8)" ::: "memory");
    } else {
      asm volatile("s_waitcnt vmcnt(0)" ::: "memory");
    }
    __syncthreads();
    if (tid == 0)
      __hip_atomic_store(flags + (size_t)t * NBLK_ + by * 32 + bx, 1u,
                         __ATOMIC_RELAXED, __HIP_MEMORY_SCOPE_AGENT);

    // epilogue pass 2 (off critical path): head partials; slot = (bx<<1)|qn of 64
    float* partW = partAll + (size_t)t * PARTSZ_;
#pragma unroll
    for (int mi = 0; mi < 4; ++mi) {
#pragma unroll
      for (int r = 0; r < 4; ++r) {
        int b = m0 + qm * 64 + mi * 16 + rbase + r;
        float p0 = creg[mi][r] * w0, p1 = creg[mi][r] * w1;
#pragma unroll
        for (int off = 1; off < 16; off <<= 1) {
          p0 += __shfl_xor(p0, off);
          p1 += __shfl_xor(p1, off);
        }
        if (cbase == 0) {
          partW[(b << 7) + (bx << 1) + qn] = p0;
          partW[(b << 7) + 64 + (bx << 1) + qn] = p1;
        }
      }
    }
  }
}

// ---------- final: reduce ALL steps' partials -> out[t] log-softmax; t=63 also raw out_final
__global__ void final_kernel(const float* __restrict__ partAll, const float* __restrict__ bout,
                             float* __restrict__ out) {
  int gid = blockIdx.x * 256 + threadIdx.x;  // 131072 = 64 t x 1024 b x 2 cls
  int t = gid >> 11;
  int r = gid & 2047;
  int b = r >> 1, cls = r & 1;
  const float4* pp = (const float4*)(partAll + (size_t)t * PARTSZ_ + (b << 7) + cls * 64);
  float4 sv = {0.f, 0.f, 0.f, 0.f};
#pragma unroll
  for (int q = 0; q < 16; ++q) {
    float4 v = pp[q];
    sv.x += v.x; sv.y += v.y; sv.z += v.z; sv.w += v.w;
  }
  float l = sv.x + sv.y + sv.z + sv.w + bout[cls];
  float other = __shfl_xor(l, 1);
  float m = fmaxf(l, other);
  float ls = m + __logf(__expf(l - m) + __expf(other - m));
  out[(size_t)t * (B_ * 2) + b * 2 + cls] = l - ls;
  if (t == 63) out[(size_t)T_ * (B_ * 2) + b * 2 + cls] = l;  // out_final raw
}

extern "C" void kernel_launch(void* const* d_in, const int* in_sizes, int n_in,
                              void* d_out, int out_size, void* d_ws, size_t ws_size,
                              hipStream_t stream) {
  const int* x      = (const int*)d_in[0];
  const float* emb  = (const float*)d_in[1];
  const float* W_ih = (const float*)d_in[2];
  const float* W_hh = (const float*)d_in[3];
  const float* b_ih = (const float*)d_in[4];
  const float* b_hh = (const float*)d_in[5];
  const float* W_out = (const float*)d_in[6];
  const float* b_out = (const float*)d_in[7];
  const float* h0   = (const float*)d_in[8];
  const float* c0   = (const float*)d_in[9];
  float* out = (float*)d_out;

  // workspace (~691 MB): XEall region is DEAD after xproj -> reused as the h ring.
  char* w = (char*)d_ws;
  u16* WihP = (u16*)w;   w += (size_t)G4_ * H_ * 2;             // 8 MB
  u16* WhhP = (u16*)w;   w += (size_t)G4_ * H_ * 2;             // 8 MB
  u16* XEall = (u16*)w;  w += (size_t)T_ * HB_ * 2;             // 128 MB (= hring[1..64])
  u16* GXall = (u16*)w;  w += (size_t)T_ * B_ * G4_ * 2;        // 512 MB
  u16* h0slot = (u16*)w; w += (size_t)HB_ * 2;                  // 2 MB (hring[0])
  float* bcP = (float*)w;     w += (size_t)G4_ * 4;
  float* partAll = (float*)w; w += (size_t)T_ * PARTSZ_ * 4;    // 32 MB
  u32* flags = (u32*)w;       w += (size_t)T_ * NBLK_ * 4;      // 64 KB

  prep_kernel<<<5137, 256, 0, stream>>>(W_ih, W_hh, b_ih, b_hh, h0,
                                        WihP, WhhP, bcP, h0slot, flags);
  gather_kernel<<<dim3(B_, T_), 256, 0, stream>>>(x, emb, XEall);
  xproj_kernel<<<8192, 512, 0, stream>>>(XEall, WihP, bcP, GXall);
  rec_kernel<<<NBLK_, 256, 0, stream>>>(h0slot, XEall /*hring[1..]*/, WhhP, GXall, c0,
                                        partAll, W_out, flags);
  final_kernel<<<512, 256, 0, stream>>>(partAll, b_out, out);
}

// Round 18
// 1601.441 us; speedup vs baseline: 1.2663x; 1.0748x over previous
//
#include <hip/hip_runtime.h>

typedef __bf16 bf16x8 __attribute__((ext_vector_type(8)));
typedef float f32x4 __attribute__((ext_vector_type(4)));
typedef unsigned short u16;
typedef unsigned int u32;

#define T_ 64
#define B_ 1024
#define H_ 1024
#define G4_ 4096
#define HB_ (B_ * H_)
#define NBLK_ 512
#define PARTSZ_ (B_ * 2 * 64)

__device__ inline u16 f2bf(float f) {
  u32 u = __float_as_uint(f);
  u32 r = (u + 0x7fffu + ((u >> 16) & 1u)) >> 16;  // RNE
  return (u16)r;
}

__device__ inline float bf2f(u16 v) { return __uint_as_float((u32)v << 16); }

__device__ inline uint2 cvt4(float4 v) {
  uint2 r;
  r.x = (u32)f2bf(v.x) | ((u32)f2bf(v.y) << 16);
  r.y = (u32)f2bf(v.z) | ((u32)f2bf(v.w) << 16);
  return r;
}

__device__ __forceinline__ void gload16(const void* g, void* l) {
  __builtin_amdgcn_global_load_lds(
      (const __attribute__((address_space(1))) unsigned int*)g,
      (__attribute__((address_space(3))) unsigned int*)l, 16, 0, 0);
}

// write-through 2B store: data lands at the coherence point (L3), never dirty in L2.
__device__ __forceinline__ void store_wt16(u16* p, u16 v) {
  asm volatile("global_store_short %0, %1, off sc0 sc1" :: "v"(p), "v"((u32)v) : "memory");
}

__device__ inline float fsig(float x) { return 1.f / (1.f + __expf(-x)); }
__device__ inline float ftanh(float x) {
  float e = __expf(2.f * x);
  return 1.f - 2.f / (e + 1.f);
}

// ---------- prep: WihP/WhhP gate-interleaved-row bf16 [4096][1024], bcP permuted bias,
// h0slot=bf16(h0), flags[64][512]=0.  Permutation: n' = (j>>4)*64 + gate*16 + (j&15)
__global__ void prep_kernel(const float* __restrict__ W_ih, const float* __restrict__ W_hh,
                            const float* __restrict__ b_ih, const float* __restrict__ b_hh,
                            const float* __restrict__ h0,
                            u16* __restrict__ WihP, u16* __restrict__ WhhP,
                            float* __restrict__ bcP, u16* __restrict__ h0slot,
                            u32* __restrict__ flags) {
  int bid = blockIdx.x, tid = threadIdx.x;
  if (bid < 4096) {
    int np = bid;
    int gate = (np >> 4) & 3;
    int j = ((np >> 6) << 4) | (np & 15);
    size_t srow = (size_t)(gate * 1024 + j) * 1024;
    int base = tid << 2;
    *(uint2*)(WihP + (size_t)np * 1024 + base) = cvt4(*(const float4*)(W_ih + srow + base));
    *(uint2*)(WhhP + (size_t)np * 1024 + base) = cvt4(*(const float4*)(W_hh + srow + base));
  } else if (bid < 5120) {
    int i = ((bid - 4096) * 256 + tid) << 2;
    *(uint2*)(h0slot + i) = cvt4(*(const float4*)(h0 + i));
  } else if (bid == 5120) {
#pragma unroll
    for (int q = 0; q < 16; ++q) {
      int np = q * 256 + tid;
      int gate = (np >> 4) & 3;
      int j = ((np >> 6) << 4) | (np & 15);
      int srcn = gate * 1024 + j;
      bcP[np] = b_ih[srcn] + b_hh[srcn];
    }
  } else {
    int idx = ((bid - 5121) * 256 + tid) << 2;  // 32 blocks x 1024 u32 = 32768
    *(uint4*)(flags + idx) = uint4{0u, 0u, 0u, 0u};
  }
}

// ---------- gather ALL 64 steps: XEall[t][b][:] = bf16(emb[x[b,t]])
__global__ void gather_kernel(const int* __restrict__ x, const float* __restrict__ emb,
                              u16* __restrict__ XEall) {
  int b = blockIdx.x, tc = blockIdx.y;
  int row = x[b * T_ + tc];
  int e = threadIdx.x << 2;
  float4 v = *(const float4*)(emb + (size_t)row * H_ + e);
  *(uint2*)(XEall + ((size_t)tc * B_ + b) * H_ + e) = cvt4(v);
}

// ---------- x-projection big GEMM, ONE dispatch: M = 65536, N = 4096, K = 1024.
// 256x128 tile, 512 threads = 8 waves (4m x 2n of 64x64), BK=64, single LDS buffer.
// Output written in REC-CONSUMPTION order: GX2[t][L][tid][16] where L = bx*8+by,
// tid = qm*64+(rbase<<2)+cbase, slot = gate*4+r. 32B/thread/step, coalesced.
__global__ void __launch_bounds__(512, 4) xproj_kernel(
    const u16* __restrict__ XEc, const u16* __restrict__ WihP,
    const float* __restrict__ bcP, u16* __restrict__ GX2) {
  __shared__ char smem[49152];  // lsA [256][128B] (32K) + lsB [128][128B] (16K)
  const int tid = threadIdx.x;
  const int lane = tid & 63;
  const int wave = tid >> 6;
  const int wm = wave >> 1;  // [0,4)
  const int wn = wave & 1;   // [0,2)
  const int hbid = blockIdx.x;        // 8192 = 8 XCD x 1024
  const int xcd = hbid & 7;
  const int s10 = hbid >> 3;          // [0,1024)
  const int mg = s10 >> 6;            // [0,16) groups of 2 m-tiles
  const int rem = s10 & 63;
  const int n0 = (rem >> 1) * 128;    // 32 n-tiles, inner sweep
  const int m0 = (xcd * 32 + mg * 2 + (rem & 1)) * 256;  // 256 m-tiles, XCD-private

  const u16* srcA[4];
  const u16* srcB[2];
  int betaA[4], betaB[2];
#pragma unroll
  for (int s = 0; s < 4; ++s) {
    int beta = (s * 512 + tid) * 16;             // 0..32K
    int row = beta >> 7;                         // [0,256)
    int colu = (beta & 127) ^ ((row & 7) << 4);  // pre-swizzled source col
    srcA[s] = XEc + (size_t)(m0 + row) * 1024 + (colu >> 1);
    betaA[s] = beta;
  }
#pragma unroll
  for (int s = 0; s < 2; ++s) {
    int beta = (s * 512 + tid) * 16;             // 0..16K
    int row = beta >> 7;                         // [0,128)
    int colu = (beta & 127) ^ ((row & 7) << 4);
    srcB[s] = WihP + (size_t)(n0 + row) * 1024 + (colu >> 1);
    betaB[s] = 32768 + beta;
  }

  f32x4 acc[4][4] = {};
  const int rsel = lane & 15;
  const int ksel = (lane >> 4) << 4;

  for (int kt = 0; kt < 16; ++kt) {
#pragma unroll
    for (int s = 0; s < 4; ++s) gload16(srcA[s], smem + betaA[s]);
#pragma unroll
    for (int s = 0; s < 2; ++s) gload16(srcB[s], smem + betaB[s]);
#pragma unroll
    for (int s = 0; s < 4; ++s) srcA[s] += 64;
#pragma unroll
    for (int s = 0; s < 2; ++s) srcB[s] += 64;
    __syncthreads();
#pragma unroll
    for (int kk = 0; kk < 2; ++kk) {
      const int colb = kk * 64 + ksel;
      bf16x8 af[4], bfr[4];
#pragma unroll
      for (int mi = 0; mi < 4; ++mi) {
        int row = wm * 64 + mi * 16 + rsel;
        af[mi] = *(const bf16x8*)(smem + row * 128 + (colb ^ ((row & 7) << 4)));
      }
#pragma unroll
      for (int ni = 0; ni < 4; ++ni) {
        int row = wn * 64 + ni * 16 + rsel;
        bfr[ni] = *(const bf16x8*)(smem + 32768 + row * 128 + (colb ^ ((row & 7) << 4)));
      }
#pragma unroll
      for (int mi = 0; mi < 4; ++mi)
#pragma unroll
        for (int ni = 0; ni < 4; ++ni)
          acc[mi][ni] = __builtin_amdgcn_mfma_f32_16x16x32_bf16(af[mi], bfr[ni], acc[mi][ni], 0, 0, 0);
    }
    __syncthreads();
  }

  // epilogue: + bias, write in rec-consumption layout (coalesced 32B per (mi))
  const int rbase = (lane >> 4) << 2;
  const int cbase = lane & 15;
  float bc[4];
#pragma unroll
  for (int ni = 0; ni < 4; ++ni) bc[ni] = bcP[n0 + wn * 64 + ni * 16 + cbase];
  const int tstep = m0 >> 10;                 // step index
  const int bxp = (n0 >> 6) + wn;             // rec n-tile [0,64)
  const int brow0 = (m0 & 1023) + wm * 64;    // batch-row base of this wave
#pragma unroll
  for (int mi = 0; mi < 4; ++mi) {
    int brow = brow0 + mi * 16;
    int byp = brow >> 7;                      // rec m-tile [0,8)
    int qmp = (brow >> 4) & 7;                // rec wave
    int tidp = qmp * 64 + (rbase << 2) + cbase;
    size_t gb = (((size_t)tstep * NBLK_ + bxp * 8 + byp) * 512 + tidp) * 16;
    u16 vals[16];
#pragma unroll
    for (int ni = 0; ni < 4; ++ni)
#pragma unroll
      for (int r = 0; r < 4; ++r)
        vals[ni * 4 + r] = f2bf(acc[mi][ni][r] + bc[ni]);
    *(uint4*)(GX2 + gb) = *(const uint4*)vals;
    *(uint4*)(GX2 + gb + 8) = *(const uint4*)(vals + 8);
  }
}

// ---------- persistent recurrent kernel: 512 blocks x 512 thr (r13 shape), NO fences.
// 3-deep A/B LDS pipeline (prefetch distance 2 covers the ~700ns L3 latency of the
// always-L2-cold h loads). GX in REGISTERS (2 x uint4 per thread, loaded at step
// start from the rec-ordered GX2 layout). h via WT stores + fresh ring; group flags.
__global__ void __launch_bounds__(512, 4) rec_kernel(
    const u16* __restrict__ h0slot, u16* __restrict__ hring,
    const u16* __restrict__ WhhP, const u16* __restrict__ GX2,
    const float* __restrict__ c0, float* __restrict__ partAll,
    const float* __restrict__ Wout, u32* __restrict__ flags) {
  __shared__ char smem[73728];  // A ring 3x16K @0 | B ring 3x8K @49152
  const int tid = threadIdx.x;
  const int lane = tid & 63;
  const int qm = tid >> 6;  // wave = m-slice [0,8), 16 rows each
  const int hbid = blockIdx.x;
  const int L = (hbid & 7) * 64 + (hbid >> 3);  // XCD swizzle: W n-slice per XCD
  const int bx = L >> 3;   // [0,64): n-tile
  const int by = L & 7;    // [0,8): m-tile
  const int n0 = bx * 64;
  const int m0 = by * 128;

  int offA[2], betaS[2];
  int offB, betaB;
#pragma unroll
  for (int s = 0; s < 2; ++s) {
    int beta = (s * 512 + tid) * 16;             // 0..16K
    int row = beta >> 7;
    int colu = (beta & 127) ^ ((row & 7) << 4);
    offA[s] = (m0 + row) * 1024 + (colu >> 1);
    betaS[s] = beta;
  }
  {
    int beta = tid * 16;                         // 0..8K
    int row = beta >> 7;
    int colu = (beta & 127) ^ ((row & 7) << 4);
    offB = (n0 + row) * 1024 + (colu >> 1);
    betaB = beta;
  }

  const int rsel = lane & 15;
  const int ksel = (lane >> 4) << 4;
  const int rbase = (lane >> 4) << 2;
  const int cbase = lane & 15;
  const int j = bx * 16 + cbase;
  const float w0 = Wout[j], w1 = Wout[1024 + j];

  // GX2 pointer for this (block, thread): step stride = NBLK_*512*16 u16
  const u16* gptr = GX2 + ((size_t)(bx * 8 + by) * 512 + tid) * 16;

  // cell state lives in registers for the whole sequence (4 rows per thread)
  float creg[4];
#pragma unroll
  for (int r = 0; r < 4; ++r)
    creg[r] = c0[(size_t)(m0 + qm * 16 + rbase + r) * H_ + j];

#pragma unroll 1
  for (int t = 0; t < T_; ++t) {
    // GX(t) -> registers (consumed in epilogue; latency hidden by the whole K-loop)
    const u16* gp = gptr + (size_t)t * (NBLK_ * 512 * 16);
    uint4 gxa = *(const uint4*)gp;
    uint4 gxb = *(const uint4*)(gp + 8);

    // B(Whh) tile 0 -> buffer 0: barrier-independent, issue before the poll.
    gload16(WhhP + offB, smem + 49152 + betaB);

    if (t) {
      // group barrier: wait for the 64 same-by blocks (they wrote our h rows, step t-1)
      if (tid < 64) {
        const u32* fg = flags + (size_t)(t - 1) * NBLK_ + by * 64;
        int guard = 0;
        while (true) {
          u32 v = __hip_atomic_load(fg + tid, __ATOMIC_RELAXED, __HIP_MEMORY_SCOPE_AGENT);
          if (__all(v != 0)) break;
          __builtin_amdgcn_s_sleep(4);
          if (++guard > (1 << 18)) break;  // bounded: fail loud, never hang
        }
      }
      __syncthreads();  // no acquire fence: h buffer fresh, L2 never cached it
    }

    // h ring: step t reads hring[t-1] (t=0 -> h0slot), writes hring[t]
    const u16* hbR = t ? (hring + (size_t)(t - 1) * HB_) : h0slot;
    u16* hbW = hring + (size_t)t * HB_;

    // A tile 0 (post-barrier) + full tile 1 -> ring slots 0,1
#pragma unroll
    for (int s = 0; s < 2; ++s) gload16(hbR + offA[s], smem + betaS[s]);
#pragma unroll
    for (int s = 0; s < 2; ++s) gload16(hbR + offA[s] + 64, smem + 16384 + betaS[s]);
    gload16(WhhP + offB + 64, smem + 49152 + 8192 + betaB);

    f32x4 acc[4] = {};
#pragma unroll
    for (int kt = 0; kt < 16; ++kt) {
      const int cur = kt % 3;
      const int abase = cur * 16384;
      const int bbase = 49152 + cur * 8192;
      if (kt < 14) {
        const int nxt = (kt + 2) % 3;
        const int kadv = (kt + 2) * 64;
#pragma unroll
        for (int s = 0; s < 2; ++s)
          gload16(hbR + offA[s] + kadv, smem + nxt * 16384 + betaS[s]);
        gload16(WhhP + offB + kadv, smem + 49152 + nxt * 8192 + betaB);
        // 3-deep: after issue, <= 2 tiles (+GX regs) beyond current in flight;
        // vmcnt(6) drains through tile kt regardless of GX placement.
        asm volatile("s_waitcnt vmcnt(6)" ::: "memory");
      } else if (kt == 14) {
        asm volatile("s_waitcnt vmcnt(3)" ::: "memory");
      } else {
        asm volatile("s_waitcnt vmcnt(0)" ::: "memory");
      }
      __builtin_amdgcn_s_barrier();
      __builtin_amdgcn_sched_barrier(0);
#pragma unroll
      for (int kk = 0; kk < 2; ++kk) {
        const int colb = kk * 64 + ksel;
        bf16x8 af, bfr[4];
        {
          int row = qm * 16 + rsel;
          af = *(const bf16x8*)(smem + abase + row * 128 + (colb ^ ((row & 7) << 4)));
        }
#pragma unroll
        for (int ni = 0; ni < 4; ++ni) {
          int row = ni * 16 + rsel;
          bfr[ni] = *(const bf16x8*)(smem + bbase + row * 128 + (colb ^ ((row & 7) << 4)));
        }
#pragma unroll
        for (int ni = 0; ni < 4; ++ni)
          acc[ni] = __builtin_amdgcn_mfma_f32_16x16x32_bf16(af, bfr[ni], acc[ni], 0, 0, 0);
      }
      __builtin_amdgcn_s_barrier();
      __builtin_amdgcn_sched_barrier(0);
    }

    // epilogue pass 1: gates = acc + gx(REGISTERS); cell on register c; WT h stores
    u16 gxs[16];
    *(uint4*)gxs = gxa;
    *(uint4*)(gxs + 8) = gxb;
#pragma unroll
    for (int r = 0; r < 4; ++r) {
      int b = m0 + qm * 16 + rbase + r;
      float gi = acc[0][r] + bf2f(gxs[r]);
      float gf = acc[1][r] + bf2f(gxs[4 + r]);
      float gg = acc[2][r] + bf2f(gxs[8 + r]);
      float go = acc[3][r] + bf2f(gxs[12 + r]);
      float c2 = fsig(gf) * creg[r] + fsig(gi) * ftanh(gg);
      float h2 = fsig(go) * ftanh(c2);
      creg[r] = c2;
      store_wt16(hbW + (size_t)b * H_ + j, f2bf(h2));
    }

    // drain h stores -> coherence point, then signal
    asm volatile("s_waitcnt vmcnt(0)" ::: "memory");
    __syncthreads();
    if (tid == 0)
      __hip_atomic_store(flags + (size_t)t * NBLK_ + by * 64 + bx, 1u,
                         __ATOMIC_RELAXED, __HIP_MEMORY_SCOPE_AGENT);

    // epilogue pass 2 (off critical path): head partials from creg
    float* partW = partAll + (size_t)t * PARTSZ_;
#pragma unroll
    for (int r = 0; r < 4; ++r) {
      int b = m0 + qm * 16 + rbase + r;
      float p0 = creg[r] * w0, p1 = creg[r] * w1;
#pragma unroll
      for (int off = 1; off < 16; off <<= 1) {
        p0 += __shfl_xor(p0, off);
        p1 += __shfl_xor(p1, off);
      }
      if (cbase == 0) {
        partW[(b << 7) + bx] = p0;
        partW[(b << 7) + 64 + bx] = p1;
      }
    }
  }
}

// ---------- final: reduce ALL steps' partials -> out[t] log-softmax; t=63 also raw out_final
__global__ void final_kernel(const float* __restrict__ partAll, const float* __restrict__ bout,
                             float* __restrict__ out) {
  int gid = blockIdx.x * 256 + threadIdx.x;  // 131072 = 64 t x 1024 b x 2 cls
  int t = gid >> 11;
  int r = gid & 2047;
  int b = r >> 1, cls = r & 1;
  const float4* pp = (const float4*)(partAll + (size_t)t * PARTSZ_ + (b << 7) + cls * 64);
  float4 sv = {0.f, 0.f, 0.f, 0.f};
#pragma unroll
  for (int q = 0; q < 16; ++q) {
    float4 v = pp[q];
    sv.x += v.x; sv.y += v.y; sv.z += v.z; sv.w += v.w;
  }
  float l = sv.x + sv.y + sv.z + sv.w + bout[cls];
  float other = __shfl_xor(l, 1);
  float m = fmaxf(l, other);
  float ls = m + __logf(__expf(l - m) + __expf(other - m));
  out[(size_t)t * (B_ * 2) + b * 2 + cls] = l - ls;
  if (t == 63) out[(size_t)T_ * (B_ * 2) + b * 2 + cls] = l;  // out_final raw
}

extern "C" void kernel_launch(void* const* d_in, const int* in_sizes, int n_in,
                              void* d_out, int out_size, void* d_ws, size_t ws_size,
                              hipStream_t stream) {
  const int* x      = (const int*)d_in[0];
  const float* emb  = (const float*)d_in[1];
  const float* W_ih = (const float*)d_in[2];
  const float* W_hh = (const float*)d_in[3];
  const float* b_ih = (const float*)d_in[4];
  const float* b_hh = (const float*)d_in[5];
  const float* W_out = (const float*)d_in[6];
  const float* b_out = (const float*)d_in[7];
  const float* h0   = (const float*)d_in[8];
  const float* c0   = (const float*)d_in[9];
  float* out = (float*)d_out;

  // workspace (~691 MB): XEall region is DEAD after xproj -> reused as the h ring.
  char* w = (char*)d_ws;
  u16* WihP = (u16*)w;   w += (size_t)G4_ * H_ * 2;             // 8 MB
  u16* WhhP = (u16*)w;   w += (size_t)G4_ * H_ * 2;             // 8 MB
  u16* XEall = (u16*)w;  w += (size_t)T_ * HB_ * 2;             // 128 MB (= hring[1..64])
  u16* GX2  = (u16*)w;   w += (size_t)T_ * NBLK_ * 512 * 16 * 2;  // 512 MB rec-ordered
  u16* h0slot = (u16*)w; w += (size_t)HB_ * 2;                  // 2 MB (hring[0])
  float* bcP = (float*)w;     w += (size_t)G4_ * 4;
  float* partAll = (float*)w; w += (size_t)T_ * PARTSZ_ * 4;    // 32 MB
  u32* flags = (u32*)w;       w += (size_t)T_ * NBLK_ * 4;      // 128 KB

  prep_kernel<<<5153, 256, 0, stream>>>(W_ih, W_hh, b_ih, b_hh, h0,
                                        WihP, WhhP, bcP, h0slot, flags);
  gather_kernel<<<dim3(B_, T_), 256, 0, stream>>>(x, emb, XEall);
  xproj_kernel<<<8192, 512, 0, stream>>>(XEall, WihP, bcP, GX2);
  rec_kernel<<<NBLK_, 512, 0, stream>>>(h0slot, XEall /*hring[1..]*/, WhhP, GX2, c0,
                                        partAll, W_out, flags);
  final_kernel<<<512, 256, 0, stream>>>(partAll, b_out, out);
}

// Round 19
// 1578.129 us; speedup vs baseline: 1.2850x; 1.0148x over previous
//
#include <hip/hip_runtime.h>

typedef __bf16 bf16x8 __attribute__((ext_vector_type(8)));
typedef float f32x4 __attribute__((ext_vector_type(4)));
typedef unsigned short u16;
typedef unsigned int u32;

#define T_ 64
#define B_ 1024
#define H_ 1024
#define G4_ 4096
#define HB_ (B_ * H_)
#define NBLK_ 512
#define PARTSZ_ (B_ * 2 * 64)

__device__ inline u16 f2bf(float f) {
  u32 u = __float_as_uint(f);
  u32 r = (u + 0x7fffu + ((u >> 16) & 1u)) >> 16;  // RNE
  return (u16)r;
}

__device__ inline float bf2f(u16 v) { return __uint_as_float((u32)v << 16); }

__device__ inline uint2 cvt4(float4 v) {
  uint2 r;
  r.x = (u32)f2bf(v.x) | ((u32)f2bf(v.y) << 16);
  r.y = (u32)f2bf(v.z) | ((u32)f2bf(v.w) << 16);
  return r;
}

__device__ __forceinline__ void gload16(const void* g, void* l) {
  __builtin_amdgcn_global_load_lds(
      (const __attribute__((address_space(1))) unsigned int*)g,
      (__attribute__((address_space(3))) unsigned int*)l, 16, 0, 0);
}

// write-through 2B store: data lands at the coherence point (L3), never dirty in L2.
__device__ __forceinline__ void store_wt16(u16* p, u16 v) {
  asm volatile("global_store_short %0, %1, off sc0 sc1" :: "v"(p), "v"((u32)v) : "memory");
}

__device__ inline float fsig(float x) { return 1.f / (1.f + __expf(-x)); }
__device__ inline float ftanh(float x) {
  float e = __expf(2.f * x);
  return 1.f - 2.f / (e + 1.f);
}

// ---------- prep: WihP/WhhP gate-interleaved-row bf16 [4096][1024], bcP permuted bias,
// h0slot=bf16(h0), flags[64][512]=0.  Permutation: n' = (j>>4)*64 + gate*16 + (j&15)
__global__ void prep_kernel(const float* __restrict__ W_ih, const float* __restrict__ W_hh,
                            const float* __restrict__ b_ih, const float* __restrict__ b_hh,
                            const float* __restrict__ h0,
                            u16* __restrict__ WihP, u16* __restrict__ WhhP,
                            float* __restrict__ bcP, u16* __restrict__ h0slot,
                            u32* __restrict__ flags) {
  int bid = blockIdx.x, tid = threadIdx.x;
  if (bid < 4096) {
    int np = bid;
    int gate = (np >> 4) & 3;
    int j = ((np >> 6) << 4) | (np & 15);
    size_t srow = (size_t)(gate * 1024 + j) * 1024;
    int base = tid << 2;
    *(uint2*)(WihP + (size_t)np * 1024 + base) = cvt4(*(const float4*)(W_ih + srow + base));
    *(uint2*)(WhhP + (size_t)np * 1024 + base) = cvt4(*(const float4*)(W_hh + srow + base));
  } else if (bid < 5120) {
    int i = ((bid - 4096) * 256 + tid) << 2;
    *(uint2*)(h0slot + i) = cvt4(*(const float4*)(h0 + i));
  } else if (bid == 5120) {
#pragma unroll
    for (int q = 0; q < 16; ++q) {
      int np = q * 256 + tid;
      int gate = (np >> 4) & 3;
      int j = ((np >> 6) << 4) | (np & 15);
      int srcn = gate * 1024 + j;
      bcP[np] = b_ih[srcn] + b_hh[srcn];
    }
  } else {
    int idx = ((bid - 5121) * 256 + tid) << 2;  // 32 blocks x 1024 u32 = 32768
    *(uint4*)(flags + idx) = uint4{0u, 0u, 0u, 0u};
  }
}

// ---------- gather ALL 64 steps: XEall[t][b][:] = bf16(emb[x[b,t]])
__global__ void gather_kernel(const int* __restrict__ x, const float* __restrict__ emb,
                              u16* __restrict__ XEall) {
  int b = blockIdx.x, tc = blockIdx.y;
  int row = x[b * T_ + tc];
  int e = threadIdx.x << 2;
  float4 v = *(const float4*)(emb + (size_t)row * H_ + e);
  *(uint2*)(XEall + ((size_t)tc * B_ + b) * H_ + e) = cvt4(v);
}

// ---------- x-projection big GEMM, ONE dispatch: M = 65536, N = 4096, K = 1024.
// 256x128 tile, 512 threads = 8 waves (4m x 2n of 64x64), BK=64, single LDS buffer.
// Output written in REC-CONSUMPTION order: GX2[t][L][tid][16] where L = bx*8+by,
// tid = qm*64+(rbase<<2)+cbase, slot = gate*4+r. 32B/thread/step, coalesced.
__global__ void __launch_bounds__(512, 4) xproj_kernel(
    const u16* __restrict__ XEc, const u16* __restrict__ WihP,
    const float* __restrict__ bcP, u16* __restrict__ GX2) {
  __shared__ char smem[49152];  // lsA [256][128B] (32K) + lsB [128][128B] (16K)
  const int tid = threadIdx.x;
  const int lane = tid & 63;
  const int wave = tid >> 6;
  const int wm = wave >> 1;  // [0,4)
  const int wn = wave & 1;   // [0,2)
  const int hbid = blockIdx.x;        // 8192 = 8 XCD x 1024
  const int xcd = hbid & 7;
  const int s10 = hbid >> 3;          // [0,1024)
  const int mg = s10 >> 6;            // [0,16) groups of 2 m-tiles
  const int rem = s10 & 63;
  const int n0 = (rem >> 1) * 128;    // 32 n-tiles, inner sweep
  const int m0 = (xcd * 32 + mg * 2 + (rem & 1)) * 256;  // 256 m-tiles, XCD-private

  const u16* srcA[4];
  const u16* srcB[2];
  int betaA[4], betaB[2];
#pragma unroll
  for (int s = 0; s < 4; ++s) {
    int beta = (s * 512 + tid) * 16;             // 0..32K
    int row = beta >> 7;                         // [0,256)
    int colu = (beta & 127) ^ ((row & 7) << 4);  // pre-swizzled source col
    srcA[s] = XEc + (size_t)(m0 + row) * 1024 + (colu >> 1);
    betaA[s] = beta;
  }
#pragma unroll
  for (int s = 0; s < 2; ++s) {
    int beta = (s * 512 + tid) * 16;             // 0..16K
    int row = beta >> 7;                         // [0,128)
    int colu = (beta & 127) ^ ((row & 7) << 4);
    srcB[s] = WihP + (size_t)(n0 + row) * 1024 + (colu >> 1);
    betaB[s] = 32768 + beta;
  }

  f32x4 acc[4][4] = {};
  const int rsel = lane & 15;
  const int ksel = (lane >> 4) << 4;

  for (int kt = 0; kt < 16; ++kt) {
#pragma unroll
    for (int s = 0; s < 4; ++s) gload16(srcA[s], smem + betaA[s]);
#pragma unroll
    for (int s = 0; s < 2; ++s) gload16(srcB[s], smem + betaB[s]);
#pragma unroll
    for (int s = 0; s < 4; ++s) srcA[s] += 64;
#pragma unroll
    for (int s = 0; s < 2; ++s) srcB[s] += 64;
    __syncthreads();
#pragma unroll
    for (int kk = 0; kk < 2; ++kk) {
      const int colb = kk * 64 + ksel;
      bf16x8 af[4], bfr[4];
#pragma unroll
      for (int mi = 0; mi < 4; ++mi) {
        int row = wm * 64 + mi * 16 + rsel;
        af[mi] = *(const bf16x8*)(smem + row * 128 + (colb ^ ((row & 7) << 4)));
      }
#pragma unroll
      for (int ni = 0; ni < 4; ++ni) {
        int row = wn * 64 + ni * 16 + rsel;
        bfr[ni] = *(const bf16x8*)(smem + 32768 + row * 128 + (colb ^ ((row & 7) << 4)));
      }
#pragma unroll
      for (int mi = 0; mi < 4; ++mi)
#pragma unroll
        for (int ni = 0; ni < 4; ++ni)
          acc[mi][ni] = __builtin_amdgcn_mfma_f32_16x16x32_bf16(af[mi], bfr[ni], acc[mi][ni], 0, 0, 0);
    }
    __syncthreads();
  }

  // epilogue: + bias, write in rec-consumption layout (coalesced 32B per (mi))
  const int rbase = (lane >> 4) << 2;
  const int cbase = lane & 15;
  float bc[4];
#pragma unroll
  for (int ni = 0; ni < 4; ++ni) bc[ni] = bcP[n0 + wn * 64 + ni * 16 + cbase];
  const int tstep = m0 >> 10;                 // step index
  const int bxp = (n0 >> 6) + wn;             // rec n-tile [0,64)
  const int brow0 = (m0 & 1023) + wm * 64;    // batch-row base of this wave
#pragma unroll
  for (int mi = 0; mi < 4; ++mi) {
    int brow = brow0 + mi * 16;
    int byp = brow >> 7;                      // rec m-tile [0,8)
    int qmp = (brow >> 4) & 7;                // rec wave
    int tidp = qmp * 64 + (rbase << 2) + cbase;
    size_t gb = (((size_t)tstep * NBLK_ + bxp * 8 + byp) * 512 + tidp) * 16;
    u16 vals[16];
#pragma unroll
    for (int ni = 0; ni < 4; ++ni)
#pragma unroll
      for (int r = 0; r < 4; ++r)
        vals[ni * 4 + r] = f2bf(acc[mi][ni][r] + bc[ni]);
    *(uint4*)(GX2 + gb) = *(const uint4*)vals;
    *(uint4*)(GX2 + gb + 8) = *(const uint4*)(vals + 8);
  }
}

// ---------- persistent recurrent kernel: 512 blocks x 512 thr, r13-proven 2-deep
// schedule, NO fences. GX in REGISTERS via NT loads (no L2 pollution, no LDS staging,
// no epilogue LDS reads). h via WT stores + fresh ring; per-group flag barrier.
__global__ void __launch_bounds__(512, 4) rec_kernel(
    const u16* __restrict__ h0slot, u16* __restrict__ hring,
    const u16* __restrict__ WhhP, const u16* __restrict__ GX2,
    const float* __restrict__ c0, float* __restrict__ partAll,
    const float* __restrict__ Wout, u32* __restrict__ flags) {
  __shared__ char smem[49152];  // A dbuf 2x16K @0 | B dbuf 2x8K @32768
  const int tid = threadIdx.x;
  const int lane = tid & 63;
  const int qm = tid >> 6;  // wave = m-slice [0,8), 16 rows each
  const int hbid = blockIdx.x;
  const int L = (hbid & 7) * 64 + (hbid >> 3);  // XCD swizzle: W n-slice per XCD
  const int bx = L >> 3;   // [0,64): n-tile
  const int by = L & 7;    // [0,8): m-tile
  const int n0 = bx * 64;
  const int m0 = by * 128;

  int offA[2], betaS[2];
  int offB, betaB;
#pragma unroll
  for (int s = 0; s < 2; ++s) {
    int beta = (s * 512 + tid) * 16;             // 0..16K
    int row = beta >> 7;
    int colu = (beta & 127) ^ ((row & 7) << 4);
    offA[s] = (m0 + row) * 1024 + (colu >> 1);
    betaS[s] = beta;
  }
  {
    int beta = tid * 16;                         // 0..8K
    int row = beta >> 7;
    int colu = (beta & 127) ^ ((row & 7) << 4);
    offB = (n0 + row) * 1024 + (colu >> 1);
    betaB = beta;
  }

  const int rsel = lane & 15;
  const int ksel = (lane >> 4) << 4;
  const int rbase = (lane >> 4) << 2;
  const int cbase = lane & 15;
  const int j = bx * 16 + cbase;
  const float w0 = Wout[j], w1 = Wout[1024 + j];

  // GX2 pointer for this (block, thread): step stride = NBLK_*512*16 u16
  const u16* gptr = GX2 + ((size_t)(bx * 8 + by) * 512 + tid) * 16;

  // cell state lives in registers for the whole sequence (4 rows per thread)
  float creg[4];
#pragma unroll
  for (int r = 0; r < 4; ++r)
    creg[r] = c0[(size_t)(m0 + qm * 16 + rbase + r) * H_ + j];

#pragma unroll 1
  for (int t = 0; t < T_; ++t) {
    // GX(t) -> registers via NT loads (read-once: don't allocate in L2/L3).
    // Oldest in vmcnt queue; drained by kt0's vmcnt(3); used only after kt15's vmcnt(0).
    const u16* gp = gptr + (size_t)t * (NBLK_ * 512 * 16);
    uint4 gxa, gxb;
    asm volatile(
        "global_load_dwordx4 %0, %2, off nt\n\t"
        "global_load_dwordx4 %1, %2, off offset:16 nt"
        : "=v"(gxa), "=v"(gxb) : "v"(gp) : "memory");

    // B(Whh) tile 0 -> buffer 0: barrier-independent, issue before the poll.
    gload16(WhhP + offB, smem + 32768 + betaB);

    if (t) {
      // group barrier: wait for the 64 same-by blocks (they wrote our h rows, step t-1)
      if (tid < 64) {
        const u32* fg = flags + (size_t)(t - 1) * NBLK_ + by * 64;
        int guard = 0;
        while (true) {
          u32 v = __hip_atomic_load(fg + tid, __ATOMIC_RELAXED, __HIP_MEMORY_SCOPE_AGENT);
          if (__all(v != 0)) break;
          __builtin_amdgcn_s_sleep(4);
          if (++guard > (1 << 18)) break;  // bounded: fail loud, never hang
        }
      }
      __syncthreads();  // no acquire fence: h buffer fresh, L2 never cached it
    }

    // h ring: step t reads hring[t-1] (t=0 -> h0slot), writes hring[t]
    const u16* hbR = t ? (hring + (size_t)(t - 1) * HB_) : h0slot;
    u16* hbW = hring + (size_t)t * HB_;

    // A(h) tile 0 (needs the barrier)
#pragma unroll
    for (int s = 0; s < 2; ++s) gload16(hbR + offA[s], smem + betaS[s]);

    f32x4 acc[4] = {};
#pragma unroll
    for (int kt = 0; kt < 16; ++kt) {
      const int cur = kt & 1;
      const int abase = cur * 16384;
      const int bbase = 32768 + cur * 8192;
      if (kt < 15) {
        const int nab = (cur ^ 1) * 16384;
        const int nbb = 32768 + (cur ^ 1) * 8192;
        const int kadv = (kt + 1) * 64;
#pragma unroll
        for (int s = 0; s < 2; ++s) gload16(hbR + offA[s] + kadv, smem + nab + betaS[s]);
        gload16(WhhP + offB + kadv, smem + nbb + betaB);
        // steady: queue = [3 tile_kt, 3 tile_kt+1] -> vmcnt(3) drains tile kt.
        // kt0: queue = [2 GX, 1 B0, 2 A0, 3 tile1] -> vmcnt(3) drains GX+B0+A0.
        asm volatile("s_waitcnt vmcnt(3)" ::: "memory");
      } else {
        asm volatile("s_waitcnt vmcnt(0)" ::: "memory");
      }
      __builtin_amdgcn_s_barrier();
      __builtin_amdgcn_sched_barrier(0);
#pragma unroll
      for (int kk = 0; kk < 2; ++kk) {
        const int colb = kk * 64 + ksel;
        bf16x8 af, bfr[4];
        {
          int row = qm * 16 + rsel;
          af = *(const bf16x8*)(smem + abase + row * 128 + (colb ^ ((row & 7) << 4)));
        }
#pragma unroll
        for (int ni = 0; ni < 4; ++ni) {
          int row = ni * 16 + rsel;
          bfr[ni] = *(const bf16x8*)(smem + bbase + row * 128 + (colb ^ ((row & 7) << 4)));
        }
#pragma unroll
        for (int ni = 0; ni < 4; ++ni)
          acc[ni] = __builtin_amdgcn_mfma_f32_16x16x32_bf16(af, bfr[ni], acc[ni], 0, 0, 0);
      }
      __builtin_amdgcn_s_barrier();
      __builtin_amdgcn_sched_barrier(0);
    }

    // epilogue pass 1: gates = acc + gx(REGISTERS); cell on register c; WT h stores
    u16 gxs[16];
    *(uint4*)gxs = gxa;
    *(uint4*)(gxs + 8) = gxb;
#pragma unroll
    for (int r = 0; r < 4; ++r) {
      int b = m0 + qm * 16 + rbase + r;
      float gi = acc[0][r] + bf2f(gxs[r]);
      float gf = acc[1][r] + bf2f(gxs[4 + r]);
      float gg = acc[2][r] + bf2f(gxs[8 + r]);
      float go = acc[3][r] + bf2f(gxs[12 + r]);
      float c2 = fsig(gf) * creg[r] + fsig(gi) * ftanh(gg);
      float h2 = fsig(go) * ftanh(c2);
      creg[r] = c2;
      store_wt16(hbW + (size_t)b * H_ + j, f2bf(h2));
    }

    // drain h stores -> coherence point, then signal
    asm volatile("s_waitcnt vmcnt(0)" ::: "memory");
    __syncthreads();
    if (tid == 0)
      __hip_atomic_store(flags + (size_t)t * NBLK_ + by * 64 + bx, 1u,
                         __ATOMIC_RELAXED, __HIP_MEMORY_SCOPE_AGENT);

    // epilogue pass 2 (off critical path): head partials from creg
    float* partW = partAll + (size_t)t * PARTSZ_;
#pragma unroll
    for (int r = 0; r < 4; ++r) {
      int b = m0 + qm * 16 + rbase + r;
      float p0 = creg[r] * w0, p1 = creg[r] * w1;
#pragma unroll
      for (int off = 1; off < 16; off <<= 1) {
        p0 += __shfl_xor(p0, off);
        p1 += __shfl_xor(p1, off);
      }
      if (cbase == 0) {
        partW[(b << 7) + bx] = p0;
        partW[(b << 7) + 64 + bx] = p1;
      }
    }
  }
}

// ---------- final: reduce ALL steps' partials -> out[t] log-softmax; t=63 also raw out_final
__global__ void final_kernel(const float* __restrict__ partAll, const float* __restrict__ bout,
                             float* __restrict__ out) {
  int gid = blockIdx.x * 256 + threadIdx.x;  // 131072 = 64 t x 1024 b x 2 cls
  int t = gid >> 11;
  int r = gid & 2047;
  int b = r >> 1, cls = r & 1;
  const float4* pp = (const float4*)(partAll + (size_t)t * PARTSZ_ + (b << 7) + cls * 64);
  float4 sv = {0.f, 0.f, 0.f, 0.f};
#pragma unroll
  for (int q = 0; q < 16; ++q) {
    float4 v = pp[q];
    sv.x += v.x; sv.y += v.y; sv.z += v.z; sv.w += v.w;
  }
  float l = sv.x + sv.y + sv.z + sv.w + bout[cls];
  float other = __shfl_xor(l, 1);
  float m = fmaxf(l, other);
  float ls = m + __logf(__expf(l - m) + __expf(other - m));
  out[(size_t)t * (B_ * 2) + b * 2 + cls] = l - ls;
  if (t == 63) out[(size_t)T_ * (B_ * 2) + b * 2 + cls] = l;  // out_final raw
}

extern "C" void kernel_launch(void* const* d_in, const int* in_sizes, int n_in,
                              void* d_out, int out_size, void* d_ws, size_t ws_size,
                              hipStream_t stream) {
  const int* x      = (const int*)d_in[0];
  const float* emb  = (const float*)d_in[1];
  const float* W_ih = (const float*)d_in[2];
  const float* W_hh = (const float*)d_in[3];
  const float* b_ih = (const float*)d_in[4];
  const float* b_hh = (const float*)d_in[5];
  const float* W_out = (const float*)d_in[6];
  const float* b_out = (const float*)d_in[7];
  const float* h0   = (const float*)d_in[8];
  const float* c0   = (const float*)d_in[9];
  float* out = (float*)d_out;

  // workspace (~691 MB): XEall region is DEAD after xproj -> reused as the h ring.
  char* w = (char*)d_ws;
  u16* WihP = (u16*)w;   w += (size_t)G4_ * H_ * 2;             // 8 MB
  u16* WhhP = (u16*)w;   w += (size_t)G4_ * H_ * 2;             // 8 MB
  u16* XEall = (u16*)w;  w += (size_t)T_ * HB_ * 2;             // 128 MB (= hring[1..64])
  u16* GX2  = (u16*)w;   w += (size_t)T_ * NBLK_ * 512 * 16 * 2;  // 512 MB rec-ordered
  u16* h0slot = (u16*)w; w += (size_t)HB_ * 2;                  // 2 MB (hring[0])
  float* bcP = (float*)w;     w += (size_t)G4_ * 4;
  float* partAll = (float*)w; w += (size_t)T_ * PARTSZ_ * 4;    // 32 MB
  u32* flags = (u32*)w;       w += (size_t)T_ * NBLK_ * 4;      // 128 KB

  prep_kernel<<<5153, 256, 0, stream>>>(W_ih, W_hh, b_ih, b_hh, h0,
                                        WihP, WhhP, bcP, h0slot, flags);
  gather_kernel<<<dim3(B_, T_), 256, 0, stream>>>(x, emb, XEall);
  xproj_kernel<<<8192, 512, 0, stream>>>(XEall, WihP, bcP, GX2);
  rec_kernel<<<NBLK_, 512, 0, stream>>>(h0slot, XEall /*hring[1..]*/, WhhP, GX2, c0,
                                        partAll, W_out, flags);
  final_kernel<<<512, 256, 0, stream>>>(partAll, b_out, out);
}